// Round 19
// baseline (454.008 us; speedup 1.0000x reference)
//
#include <hip/hip_runtime.h>
#include <hip/hip_bf16.h>
#include <cstdint>
#include <cstddef>

#define E_N 500000
#define FD 128
#define TD 100
#define OD 128
#define NT 4
#define IND 228   // FD + TD
#define KP 256    // K padded to MFMA multiple
#define NBLK 256  // 1 block per CU
#define TPB 1024  // 16 waves = 4 types x 4 col-quarters

// workspace: converted W + combined bias
static constexpr size_t WBF_OFF   = 0;                                   // bf16[NT][OD][KP] = 262,144
static constexpr size_t BIASC_OFF = WBF_OFF + (size_t)NT * OD * KP * 2;  // float[NT][OD] = 2048
static constexpr size_t WS_NEED   = BIASC_OFF + (size_t)NT * OD * 4;

typedef __attribute__((ext_vector_type(8))) short short8;
typedef __attribute__((ext_vector_type(4))) float f32x4;

__device__ __forceinline__ unsigned short f2bf(float x) {
  union { float f; unsigned u; } v; v.f = x;
  unsigned r = v.u + 0x7fff + ((v.u >> 16) & 1);   // RNE, inputs are finite
  return (unsigned short)(r >> 16);
}

// packed f32x2 -> bf16x2 via the HIP library intrinsic (RNE). The hand-rolled
// v_cvt_pk_bf16_f32 inline asm corrupted r3/r14 (absmax ~0.85) -- banned.
__device__ __forceinline__ unsigned pack2bf(float a, float b) {
  union { __hip_bfloat162 h; unsigned u; } c;
  c.h = __float22bfloat162_rn(make_float2(a, b));
  return c.u;
}

// swizzled byte offset into the A tile: row r (0..63), k elem (0..255), bf16.
__device__ __forceinline__ int a_off(int r, int k) {
  return ((r << 9) + (k << 1)) ^ ((r & 7) << 4);
}

// W [NT][IND][OD] f32 -> Wbf [NT][OD][KP] bf16 (N-major, K zero-padded beyond 228)
__global__ void wconv_kernel(const float* __restrict__ W, unsigned short* __restrict__ Wbf) {
  int row = blockIdx.x * 4 + (threadIdx.x >> 6);   // row = t*OD + n, 0..511
  int t = row >> 7, n = row & 127;
  int k0 = (threadIdx.x & 63) << 2;
  ushort4 o;
  float v0 = (k0 + 0 < IND) ? W[((size_t)t * IND + k0 + 0) * OD + n] : 0.f;
  float v1 = (k0 + 1 < IND) ? W[((size_t)t * IND + k0 + 1) * OD + n] : 0.f;
  float v2 = (k0 + 2 < IND) ? W[((size_t)t * IND + k0 + 2) * OD + n] : 0.f;
  float v3 = (k0 + 3 < IND) ? W[((size_t)t * IND + k0 + 3) * OD + n] : 0.f;
  o.x = f2bf(v0); o.y = f2bf(v1); o.z = f2bf(v2); o.w = f2bf(v3);
  *(ushort4*)(Wbf + ((size_t)row << 8) + k0) = o;
}

__global__ void bias_kernel(const float* __restrict__ b, const float* __restrict__ temb,
                            float* __restrict__ biasc) {
  int i = threadIdx.x + blockIdx.x * 512;
  if (i < NT * OD) biasc[i] = b[i] + temb[i];
}

// Main kernel: STREAMING (r12's proven-clean memory) + register-resident W
// (r18's proven compute), fused via wave-type specialization:
// 16 waves = (type qt x col-quarter cq). Each wave holds type qt's 32-col W
// panel in 64 VGPR (loaded once) and processes EVERY 64-row tile of the
// block's contiguous edge range, storing rows where types[row]==qt.
// Reads and writes are dense sequential streams; no buckets, no atomics.
// MFMA is 4x useful work (~16us chip-wide) hidden under the memory stream.
__global__ __launch_bounds__(TPB) void gemm_kernel(
    const float* __restrict__ feats, const float* __restrict__ ts,
    const int* __restrict__ types, const float* __restrict__ freqs,
    const unsigned short* __restrict__ Wbf, const float* __restrict__ biasc,
    float* __restrict__ out) {
  __shared__ __align__(16) char smA[64 * 512];      // A bf16 [64][256], XOR-swizzled
  __shared__ __align__(16) float sfreq[NT * 128];   // per-type freqs, zero-padded

  constexpr int ntiles = (E_N + 63) >> 6;
  const int chunk = (ntiles + NBLK - 1) / NBLK;
  const int t0 = blockIdx.x * chunk;
  const int t1 = min(t0 + chunk, ntiles);
  if (t0 >= t1) return;

  const int tid = threadIdx.x;
  const int w = tid >> 6, lane = tid & 63;
  const int qt = w >> 2;            // wave's type
  const int cq = w & 3;             // wave's col quarter (32 cols)
  const int bl = lane & 15, bh = lane >> 4;
  const int r = tid >> 4, part = tid & 15;   // 64 rows, 16 threads/row, 16-elem windows

  // W fragments for type qt, cols cq*32 + n*16 + bl (first MFMA operand, A-layout)
  short8 bfrag[8][2];
  #pragma unroll
  for (int n = 0; n < 2; ++n) {
    const unsigned short* bp =
        Wbf + (((size_t)qt * OD + cq * 32 + n * 16 + bl) << 8) + (bh << 3);
    #pragma unroll
    for (int k = 0; k < 8; ++k) bfrag[k][n] = *(const short8*)(bp + k * 32);
  }
  const float4 bv0 = *(const float4*)(biasc + qt * OD + cq * 32 + bh * 4);
  const float4 bv1 = *(const float4*)(biasc + qt * OD + cq * 32 + 16 + bh * 4);

  if (tid < NT * 128) {
    int ty = tid >> 7, d = tid & 127;
    sfreq[tid] = (d < TD) ? freqs[ty * TD + d] : 0.f;
  }

  // stage this thread's 16-elem window of row r:
  // part<8 -> feats window part*16 (from pf); part>=8 -> cos time window (part-8)*16
  auto stage = [&](const float4* p, float tvv, int trr, bool valid) {
    if (!valid) return;
    if (part < 8) {
      uint4 q0, q1;
      q0.x = pack2bf(p[0].x, p[0].y); q0.y = pack2bf(p[0].z, p[0].w);
      q0.z = pack2bf(p[1].x, p[1].y); q0.w = pack2bf(p[1].z, p[1].w);
      q1.x = pack2bf(p[2].x, p[2].y); q1.y = pack2bf(p[2].z, p[2].w);
      q1.z = pack2bf(p[3].x, p[3].y); q1.w = pack2bf(p[3].z, p[3].w);
      *(uint4*)(smA + a_off(r, part * 16))     = q0;
      *(uint4*)(smA + a_off(r, part * 16 + 8)) = q1;
    } else {
      const int p8 = part - 8;
      const float* fq = &sfreq[trr * 128 + p8 * 16];
      uint4 q0, q1;
      q0.x = pack2bf(__cosf(tvv * fq[0]),  __cosf(tvv * fq[1]));
      q0.y = pack2bf(__cosf(tvv * fq[2]),  __cosf(tvv * fq[3]));
      q0.z = pack2bf(__cosf(tvv * fq[4]),  __cosf(tvv * fq[5]));
      q0.w = pack2bf(__cosf(tvv * fq[6]),  __cosf(tvv * fq[7]));
      q1.x = pack2bf(__cosf(tvv * fq[8]),  __cosf(tvv * fq[9]));
      q1.y = pack2bf(__cosf(tvv * fq[10]), __cosf(tvv * fq[11]));
      q1.z = pack2bf(__cosf(tvv * fq[12]), __cosf(tvv * fq[13]));
      q1.w = pack2bf(__cosf(tvv * fq[14]), __cosf(tvv * fq[15]));
      *(uint4*)(smA + a_off(r, FD + p8 * 16))     = q0;
      *(uint4*)(smA + a_off(r, FD + p8 * 16 + 8)) = q1;
    }
  };

  // ---- prologue: tile t0 (sequential addresses) ----
  float4 pf[4];
  float tv = 0.f; int trr = 0; bool vld = false;
  {
    int e = t0 * 64 + r;
    vld = (e < E_N);
    if (vld) {
      if (part < 8) {
        const float4* src = (const float4*)(feats + (size_t)e * FD + part * 16);
        #pragma unroll
        for (int c = 0; c < 4; ++c) pf[c] = src[c];
      } else {
        tv = ts[e]; trr = types[e];
      }
    }
  }
  __syncthreads();                 // sfreq ready
  stage(pf, tv, trr, vld);

  for (int tt = t0; tt < t1; ++tt) {
    const bool last = (tt == t1 - 1);
    __syncthreads();               // A(tt) ready

    // sequential prefetch of tile tt+1 (rides under MFMA)
    float tvb = 0.f; int trb = 0; bool vb = false;
    if (!last) {
      int e = (tt + 1) * 64 + r;
      vb = (e < E_N);
      if (vb) {
        if (part < 8) {
          const float4* src = (const float4*)(feats + (size_t)e * FD + part * 16);
          #pragma unroll
          for (int c = 0; c < 4; ++c) pf[c] = src[c];
        } else {
          tvb = ts[e]; trb = types[e];
        }
      }
    }

    // ---- MFMA per row-subtile, bias in acc-init, predicated direct store ----
    const int base = tt * 64;
    __builtin_amdgcn_s_setprio(1);
    #pragma unroll
    for (int rt = 0; rt < 4; ++rt) {
      const int row = base + rt * 16 + bl;
      const int tp = (row < E_N) ? types[row] : -1;
      f32x4 a0, a1;
      a0[0] = bv0.x; a0[1] = bv0.y; a0[2] = bv0.z; a0[3] = bv0.w;
      a1[0] = bv1.x; a1[1] = bv1.y; a1[2] = bv1.z; a1[3] = bv1.w;
      #pragma unroll
      for (int k = 0; k < 8; ++k) {
        short8 av = *(const short8*)(smA + a_off(rt * 16 + bl, k * 32 + bh * 8));
        a0 = __builtin_amdgcn_mfma_f32_16x16x32_bf16(bfrag[k][0], av, a0, 0, 0, 0);
        a1 = __builtin_amdgcn_mfma_f32_16x16x32_bf16(bfrag[k][1], av, a1, 0, 0, 0);
      }
      if (tp == qt) {                // each valid row stored exactly once (by its type's waves)
        float* dst = out + (size_t)row * OD + cq * 32 + bh * 4;
        *(f32x4*)(dst)      = a0;
        *(f32x4*)(dst + 16) = a1;
      }
    }
    __builtin_amdgcn_s_setprio(0);
    __syncthreads();               // A reads done; prefetch+stores drained; region reusable

    if (!last) {
      stage(pf, tvb, trb, vb);
      tv = tvb; trr = trb; vld = vb;
    }
  }
}

// correctness fallback if ws is too small (fp32 vector path)
__global__ void naive_kernel(const float* __restrict__ feats, const float* __restrict__ ts,
                             const int* __restrict__ types, const float* __restrict__ W,
                             const float* __restrict__ b, const float* __restrict__ temb,
                             const float* __restrict__ freqs, float* __restrict__ out) {
  __shared__ float comb[IND];
  int e = blockIdx.x;
  int t = types[e];
  int tid = threadIdx.x;  // 128 threads
  comb[tid] = feats[(size_t)e * FD + tid];
  if (tid < TD) comb[FD + tid] = __cosf(ts[e] * freqs[t * TD + tid]);
  __syncthreads();
  float acc = b[t * OD + tid] + temb[t * OD + tid];
  for (int k = 0; k < IND; ++k) acc += comb[k] * W[((size_t)t * IND + k) * OD + tid];
  out[(size_t)e * OD + tid] = acc;
}

extern "C" void kernel_launch(void* const* d_in, const int* in_sizes, int n_in,
                              void* d_out, int out_size, void* d_ws, size_t ws_size,
                              hipStream_t stream) {
  const float* feats = (const float*)d_in[0];
  const float* ts    = (const float*)d_in[1];
  const int*   types = (const int*)d_in[2];
  const float* W     = (const float*)d_in[3];
  const float* bb    = (const float*)d_in[4];
  const float* temb  = (const float*)d_in[5];
  const float* freqs = (const float*)d_in[6];
  float* out = (float*)d_out;

  if (ws_size < WS_NEED) {
    naive_kernel<<<E_N, 128, 0, stream>>>(feats, ts, types, W, bb, temb, freqs, out);
    return;
  }

  char* ws = (char*)d_ws;
  unsigned short* Wbf = (unsigned short*)(ws + WBF_OFF);
  float* biasc = (float*)(ws + BIASC_OFF);

  wconv_kernel<<<(NT * OD) / 4, 256, 0, stream>>>(W, Wbf);
  bias_kernel<<<1, 512, 0, stream>>>(bb, temb, biasc);
  gemm_kernel<<<NBLK, TPB, 0, stream>>>(feats, ts, types, freqs, Wbf, biasc, out);
}

// Round 20
// 181.964 us; speedup vs baseline: 2.4950x; 2.4950x over previous
//
#include <hip/hip_runtime.h>
#include <hip/hip_bf16.h>
#include <cstdint>
#include <cstddef>

#define E_N 500000
#define FD 128
#define TD 100
#define OD 128
#define NT 4
#define IND 228   // FD + TD
#define KP 256    // K padded to MFMA multiple
#define GX 256    // chunks per type for gemm
#define NB 1954   // ceil(E_N/256) histogram blocks

// workspace layout (bytes)
static constexpr size_t BUCKET_OFF = 0;                                   // int[E_N]
static constexpr size_t WBF_OFF    = 2000000;                             // bf16[NT][OD][KP]
static constexpr size_t BIASC_OFF  = WBF_OFF + (size_t)NT * OD * KP * 2;  // float[NT][OD]
static constexpr size_t CTR_OFF    = BIASC_OFF + (size_t)NT * OD * 4;     // int[16]
static constexpr size_t PART_OFF   = CTR_OFF + 64;                        // int[NB*4]
static constexpr size_t BBASE_OFF  = PART_OFF + (size_t)NB * 4 * 4;       // int[NB*4]
static constexpr size_t WS_NEED    = BBASE_OFF + (size_t)NB * 4 * 4;

typedef __attribute__((ext_vector_type(8))) short short8;
typedef __attribute__((ext_vector_type(4))) float f32x4;

__device__ __forceinline__ unsigned short f2bf(float x) {
  union { float f; unsigned u; } v; v.f = x;
  unsigned r = v.u + 0x7fff + ((v.u >> 16) & 1);   // RNE, inputs are finite
  return (unsigned short)(r >> 16);
}

// packed f32x2 -> bf16x2 via the HIP library intrinsic (RNE). The hand-rolled
// v_cvt_pk_bf16_f32 inline asm corrupted r3/r14 (absmax ~0.85) -- banned.
__device__ __forceinline__ unsigned pack2bf(float a, float b) {
  union { __hip_bfloat162 h; unsigned u; } c;
  c.h = __float22bfloat162_rn(make_float2(a, b));
  return c.u;
}

// swizzled byte offset into the A tile: row r (0..63), k elem (0..255), bf16.
__device__ __forceinline__ int a_off(int r, int k) {
  return ((r << 9) + (k << 1)) ^ ((r & 7) << 4);
}

// per-block type histogram (1 edge/thread, ballot counts, no atomics)
__global__ void hist_kernel(const int* __restrict__ types, int* __restrict__ partial, int n) {
  __shared__ int wcnt[4][NT];
  const int tid = threadIdx.x, w = tid >> 6, l = tid & 63;
  const int i = blockIdx.x * 256 + tid;
  const int t = (i < n) ? types[i] : -1;
  #pragma unroll
  for (int q = 0; q < NT; ++q) {
    unsigned long long m = __ballot(t == q);
    if (l == 0) wcnt[w][q] = (int)__popcll(m);
  }
  __syncthreads();
  if (tid < NT) {
    int s = 0;
    #pragma unroll
    for (int w2 = 0; w2 < 4; ++w2) s += wcnt[w2][tid];
    partial[blockIdx.x * NT + tid] = s;
  }
}

// single block: exclusive scan of per-block counts -> blockbase; type totals ->
// ctr[0..3]=counts, ctr[4..7]=offsets. Fused bias precompute. Deterministic.
__global__ void scan_kernel(const int* __restrict__ partial, int* __restrict__ blockbase,
                            int* __restrict__ ctr, const float* __restrict__ b,
                            const float* __restrict__ temb, float* __restrict__ biasc) {
  __shared__ int4 tsum[256];
  const int tid = threadIdx.x;
  int4 s = make_int4(0, 0, 0, 0);
  #pragma unroll
  for (int j = 0; j < 8; ++j) {
    int blk = tid * 8 + j;
    if (blk < NB) {
      const int* p = partial + blk * 4;
      s.x += p[0]; s.y += p[1]; s.z += p[2]; s.w += p[3];
    }
  }
  tsum[tid] = s;
  __syncthreads();
  if (tid == 0) {
    int4 run = make_int4(0, 0, 0, 0);
    for (int i = 0; i < 256; ++i) {
      int4 v = tsum[i]; tsum[i] = run;
      run.x += v.x; run.y += v.y; run.z += v.z; run.w += v.w;
    }
    ctr[0] = run.x; ctr[1] = run.y; ctr[2] = run.z; ctr[3] = run.w;
    int off = 0;
    ctr[4] = 0;            off += run.x;
    ctr[5] = off;          off += run.y;
    ctr[6] = off;          off += run.z;
    ctr[7] = off;
  }
  __syncthreads();
  int4 run = tsum[tid];
  #pragma unroll
  for (int j = 0; j < 8; ++j) {
    int blk = tid * 8 + j;
    if (blk < NB) {
      const int* p = partial + blk * 4;
      int* bb = blockbase + blk * 4;
      bb[0] = run.x; bb[1] = run.y; bb[2] = run.z; bb[3] = run.w;
      run.x += p[0]; run.y += p[1]; run.z += p[2]; run.w += p[3];
    }
  }
  for (int i = tid; i < NT * OD; i += 256) biasc[i] = b[i] + temb[i];
}

// W [NT][IND][OD] f32 -> Wbf [NT][OD][KP] bf16 (N-major, K zero-padded beyond 228)
__global__ void wconv_kernel(const float* __restrict__ W, unsigned short* __restrict__ Wbf) {
  int row = blockIdx.x * 4 + (threadIdx.x >> 6);   // row = t*OD + n, 0..511
  int t = row >> 7, n = row & 127;
  int k0 = (threadIdx.x & 63) << 2;
  ushort4 o;
  float v0 = (k0 + 0 < IND) ? W[((size_t)t * IND + k0 + 0) * OD + n] : 0.f;
  float v1 = (k0 + 1 < IND) ? W[((size_t)t * IND + k0 + 1) * OD + n] : 0.f;
  float v2 = (k0 + 2 < IND) ? W[((size_t)t * IND + k0 + 2) * OD + n] : 0.f;
  float v3 = (k0 + 3 < IND) ? W[((size_t)t * IND + k0 + 3) * OD + n] : 0.f;
  o.x = f2bf(v0); o.y = f2bf(v1); o.z = f2bf(v2); o.w = f2bf(v3);
  *(ushort4*)(Wbf + ((size_t)row << 8) + k0) = o;
}

// deterministic SORTED fill: pos = type_off + blockbase[b][t] + in-block rank.
__global__ void fill_kernel(const int* __restrict__ types, const int* __restrict__ blockbase,
                            const int* __restrict__ ctr, int* __restrict__ bucket, int n) {
  __shared__ int wcnt[4][NT];
  __shared__ int wbase[4][NT];
  const int tid = threadIdx.x, w = tid >> 6, l = tid & 63;
  const int i = blockIdx.x * 256 + tid;
  const int t = (i < n) ? types[i] : -1;
  unsigned long long m[NT];
  #pragma unroll
  for (int q = 0; q < NT; ++q) {
    m[q] = __ballot(t == q);
    if (l == 0) wcnt[w][q] = (int)__popcll(m[q]);
  }
  __syncthreads();
  if (tid < NT) {
    int q = tid, s = 0;
    #pragma unroll
    for (int w2 = 0; w2 < 4; ++w2) { wbase[w2][q] = s; s += wcnt[w2][q]; }
  }
  __syncthreads();
  if (t >= 0) {
    int rank = wbase[w][t] + (int)__popcll(m[t] & ((1ull << l) - 1ull));
    bucket[ctr[4 + t] + blockbase[blockIdx.x * 4 + t] + rank] = i;
  }
}

// Main kernel: r18 (champion, 147us) + 2-DEEP register prefetch. Two NAMED
// buffers pfA/pfB (loop unrolled x2 -> all compile-time indexing, rule #20);
// loads for tile tt+2 issue at iteration tt, right after stage(tt) frees the
// buffer -> in-flight window grows from ~1 MFMA phase to ~2 full iterations,
// covering the queued-HBM gather latency that left ~7k cyc/tile exposed.
__global__ __launch_bounds__(256) void gemm_kernel(
    const float* __restrict__ feats, const float* __restrict__ ts,
    const float* __restrict__ freqs, const unsigned short* __restrict__ Wbf,
    const float* __restrict__ biasc, const int* __restrict__ bucket,
    const int* __restrict__ ctr, float* __restrict__ out) {
  __shared__ __align__(16) char smA[64 * 512];      // A bf16 [64][256], XOR-swizzled
  __shared__ __align__(16) float sfreq[128];

  const int t = blockIdx.x;
  const int cnt = ctr[t];
  const int off = ctr[4 + t];
  const int ntiles = (cnt + 63) >> 6;
  const int chunk = (ntiles + GX - 1) / GX;
  const int t0 = blockIdx.y * chunk;
  const int t1 = min(t0 + chunk, ntiles);
  if (t0 >= t1) return;

  const int tid = threadIdx.x;
  const int wid = tid >> 6, lane = tid & 63;
  const int bl = lane & 15, bh = lane >> 4;
  const int r = tid >> 2, part = tid & 3;   // 4 threads per A-row; part = 32-elem window

  // W fragments, first MFMA operand (A-layout): lane bl <-> out-col, k-window bh*8
  short8 bfrag[8][2];
  #pragma unroll
  for (int n = 0; n < 2; ++n) {
    const unsigned short* bp =
        Wbf + (((size_t)t * OD + wid * 32 + n * 16 + bl) << 8) + (bh << 3);
    #pragma unroll
    for (int k = 0; k < 8; ++k) bfrag[k][n] = *(const short8*)(bp + k * 32);
  }
  // bias for this lane's cols: col = wid*32 + n*16 + bh*4 + j
  const float4 bv0 = *(const float4*)(biasc + t * OD + wid * 32 + bh * 4);
  const float4 bv1 = *(const float4*)(biasc + t * OD + wid * 32 + 16 + bh * 4);

  if (tid < 128) sfreq[tid] = (tid < TD) ? freqs[t * TD + tid] : 0.f;

  auto stage = [&](const float4* p, float tvv) {
    #pragma unroll
    for (int j = 0; j < 4; ++j) {
      uint4 q;
      q.x = pack2bf(p[2 * j].x, p[2 * j].y);
      q.y = pack2bf(p[2 * j].z, p[2 * j].w);
      q.z = pack2bf(p[2 * j + 1].x, p[2 * j + 1].y);
      q.w = pack2bf(p[2 * j + 1].z, p[2 * j + 1].w);
      *(uint4*)(smA + a_off(r, part * 32 + 8 * j)) = q;
    }
    #pragma unroll
    for (int j = 0; j < 4; ++j) {
      float4 f0 = *(const float4*)&sfreq[part * 32 + 8 * j];
      float4 f1 = *(const float4*)&sfreq[part * 32 + 8 * j + 4];
      uint4 q;
      q.x = pack2bf(__cosf(tvv * f0.x), __cosf(tvv * f0.y));
      q.y = pack2bf(__cosf(tvv * f0.z), __cosf(tvv * f0.w));
      q.z = pack2bf(__cosf(tvv * f1.x), __cosf(tvv * f1.y));
      q.w = pack2bf(__cosf(tvv * f1.z), __cosf(tvv * f1.w));
      *(uint4*)(smA + a_off(r, FD + part * 32 + 8 * j)) = q;
    }
  };

  // issue gather for `tile` into pf/tv; returns edge index (-1 invalid)
  auto fill = [&](int tile, float4* pf, float& tv) -> int {
    int e = -1;
    if (tile < t1 && r < cnt - tile * 64) {
      e = bucket[off + tile * 64 + r];
      tv = ts[e];
      const float4* src = (const float4*)(feats + (size_t)e * FD + part * 32);
      #pragma unroll
      for (int c = 0; c < 8; ++c) pf[c] = src[c];
    }
    return e;
  };

  // MFMA on the staged tile tt, bias in acc-init, predicated direct store
  auto mfma_store = [&](int tt) {
    const int base = tt * 64;
    const int vcnt = cnt - base;
    int se[4];
    #pragma unroll
    for (int rt = 0; rt < 4; ++rt) {
      int rr = rt * 16 + bl;
      se[rt] = (rr < vcnt) ? bucket[off + base + rr] : -1;
    }
    __builtin_amdgcn_s_setprio(1);
    #pragma unroll
    for (int rt = 0; rt < 4; ++rt) {
      f32x4 a0, a1;
      a0[0] = bv0.x; a0[1] = bv0.y; a0[2] = bv0.z; a0[3] = bv0.w;
      a1[0] = bv1.x; a1[1] = bv1.y; a1[2] = bv1.z; a1[3] = bv1.w;
      #pragma unroll
      for (int k = 0; k < 8; ++k) {
        short8 av = *(const short8*)(smA + a_off(rt * 16 + bl, k * 32 + bh * 8));
        a0 = __builtin_amdgcn_mfma_f32_16x16x32_bf16(bfrag[k][0], av, a0, 0, 0, 0);
        a1 = __builtin_amdgcn_mfma_f32_16x16x32_bf16(bfrag[k][1], av, a1, 0, 0, 0);
      }
      if (se[rt] >= 0) {
        float* dst = out + (size_t)se[rt] * OD + wid * 32 + bh * 4;
        *(f32x4*)(dst)      = a0;
        *(f32x4*)(dst + 16) = a1;
      }
    }
    __builtin_amdgcn_s_setprio(0);
  };

  // ---- prologue: pfA <- t0, pfB <- t0+1 ----
  float4 pfA[8], pfB[8];
  float tvA = 0.f, tvB = 0.f;
  int eA = fill(t0, pfA, tvA);
  int eB = fill(t0 + 1, pfB, tvB);
  __syncthreads();                    // sfreq visible
  if (eA >= 0) stage(pfA, tvA);

  // even tiles use pfA, odd use pfB (compile-time buffer selection)
  for (int tt = t0; tt < t1; tt += 2) {
    __syncthreads();                  // A(tt) ready
    eA = fill(tt + 2, pfA, tvA);      // pfA freed by stage(tt); window = 2 iters
    mfma_store(tt);
    __syncthreads();                  // A reads + stores drained; region reusable
    if (tt + 1 >= t1) break;
    if (eB >= 0) stage(pfB, tvB);     // stage tile tt+1

    __syncthreads();                  // A(tt+1) ready
    eB = fill(tt + 3, pfB, tvB);      // pfB freed by stage(tt+1)
    mfma_store(tt + 1);
    __syncthreads();
    if (tt + 2 >= t1) break;
    if (eA >= 0) stage(pfA, tvA);     // stage tile tt+2
  }
}

// correctness fallback if ws is too small (fp32 vector path)
__global__ void naive_kernel(const float* __restrict__ feats, const float* __restrict__ ts,
                             const int* __restrict__ types, const float* __restrict__ W,
                             const float* __restrict__ b, const float* __restrict__ temb,
                             const float* __restrict__ freqs, float* __restrict__ out) {
  __shared__ float comb[IND];
  int e = blockIdx.x;
  int t = types[e];
  int tid = threadIdx.x;  // 128 threads
  comb[tid] = feats[(size_t)e * FD + tid];
  if (tid < TD) comb[FD + tid] = __cosf(ts[e] * freqs[t * TD + tid]);
  __syncthreads();
  float acc = b[t * OD + tid] + temb[t * OD + tid];
  for (int k = 0; k < IND; ++k) acc += comb[k] * W[((size_t)t * IND + k) * OD + tid];
  out[(size_t)e * OD + tid] = acc;
}

extern "C" void kernel_launch(void* const* d_in, const int* in_sizes, int n_in,
                              void* d_out, int out_size, void* d_ws, size_t ws_size,
                              hipStream_t stream) {
  const float* feats = (const float*)d_in[0];
  const float* ts    = (const float*)d_in[1];
  const int*   types = (const int*)d_in[2];
  const float* W     = (const float*)d_in[3];
  const float* bb    = (const float*)d_in[4];
  const float* temb  = (const float*)d_in[5];
  const float* freqs = (const float*)d_in[6];
  float* out = (float*)d_out;

  if (ws_size < WS_NEED) {
    naive_kernel<<<E_N, 128, 0, stream>>>(feats, ts, types, W, bb, temb, freqs, out);
    return;
  }

  char* ws = (char*)d_ws;
  int* bucket = (int*)(ws + BUCKET_OFF);
  unsigned short* Wbf = (unsigned short*)(ws + WBF_OFF);
  float* biasc = (float*)(ws + BIASC_OFF);
  int* ctr = (int*)(ws + CTR_OFF);
  int* partial = (int*)(ws + PART_OFF);
  int* blockbase = (int*)(ws + BBASE_OFF);

  hist_kernel<<<NB, 256, 0, stream>>>(types, partial, E_N);
  scan_kernel<<<1, 256, 0, stream>>>(partial, blockbase, ctr, bb, temb, biasc);
  wconv_kernel<<<(NT * OD) / 4, 256, 0, stream>>>(W, Wbf);
  fill_kernel<<<NB, 256, 0, stream>>>(types, blockbase, ctr, bucket, E_N);
  dim3 g(NT, GX);
  gemm_kernel<<<g, 256, 0, stream>>>(feats, ts, freqs, Wbf, biasc, bucket, ctr, out);
}

// Round 21
// 150.969 us; speedup vs baseline: 3.0073x; 1.2053x over previous
//
#include <hip/hip_runtime.h>
#include <hip/hip_bf16.h>
#include <cstdint>
#include <cstddef>

#define E_N 500000
#define FD 128
#define TD 100
#define OD 128
#define NT 4
#define IND 228   // FD + TD
#define KP 256    // K padded to MFMA multiple
#define GX 256    // chunks per type for gemm
#define NB 1954   // ceil(E_N/256) histogram blocks

// workspace layout (bytes)
static constexpr size_t BUCKET_OFF = 0;                                   // int[E_N]
static constexpr size_t WBF_OFF    = 2000000;                             // bf16[NT][OD][KP]
static constexpr size_t BIASC_OFF  = WBF_OFF + (size_t)NT * OD * KP * 2;  // float[NT][OD]
static constexpr size_t CTR_OFF    = BIASC_OFF + (size_t)NT * OD * 4;     // int[16]
static constexpr size_t PART_OFF   = CTR_OFF + 64;                        // int[NB*4]
static constexpr size_t BBASE_OFF  = PART_OFF + (size_t)NB * 4 * 4;       // int[NB*4]
static constexpr size_t WS_NEED    = BBASE_OFF + (size_t)NB * 4 * 4;

typedef __attribute__((ext_vector_type(8))) short short8;
typedef __attribute__((ext_vector_type(4))) float f32x4;

__device__ __forceinline__ unsigned short f2bf(float x) {
  union { float f; unsigned u; } v; v.f = x;
  unsigned r = v.u + 0x7fff + ((v.u >> 16) & 1);   // RNE, inputs are finite
  return (unsigned short)(r >> 16);
}

// packed f32x2 -> bf16x2 via the HIP library intrinsic (RNE). The hand-rolled
// v_cvt_pk_bf16_f32 inline asm corrupted r3/r14 (absmax ~0.85) -- banned.
__device__ __forceinline__ unsigned pack2bf(float a, float b) {
  union { __hip_bfloat162 h; unsigned u; } c;
  c.h = __float22bfloat162_rn(make_float2(a, b));
  return c.u;
}

// swizzled byte offset into the A tile: row r (0..63), k elem (0..255), bf16.
__device__ __forceinline__ int a_off(int r, int k) {
  return ((r << 9) + (k << 1)) ^ ((r & 7) << 4);
}

// per-block type histogram (1 edge/thread, ballot counts, no atomics)
__global__ void hist_kernel(const int* __restrict__ types, int* __restrict__ partial, int n) {
  __shared__ int wcnt[4][NT];
  const int tid = threadIdx.x, w = tid >> 6, l = tid & 63;
  const int i = blockIdx.x * 256 + tid;
  const int t = (i < n) ? types[i] : -1;
  #pragma unroll
  for (int q = 0; q < NT; ++q) {
    unsigned long long m = __ballot(t == q);
    if (l == 0) wcnt[w][q] = (int)__popcll(m);
  }
  __syncthreads();
  if (tid < NT) {
    int s = 0;
    #pragma unroll
    for (int w2 = 0; w2 < 4; ++w2) s += wcnt[w2][tid];
    partial[blockIdx.x * NT + tid] = s;
  }
}

// single block: exclusive scan of per-block counts -> blockbase; type totals ->
// ctr[0..3]=counts, ctr[4..7]=offsets. Fused bias precompute. Deterministic.
__global__ void scan_kernel(const int* __restrict__ partial, int* __restrict__ blockbase,
                            int* __restrict__ ctr, const float* __restrict__ b,
                            const float* __restrict__ temb, float* __restrict__ biasc) {
  __shared__ int4 tsum[256];
  const int tid = threadIdx.x;
  int4 s = make_int4(0, 0, 0, 0);
  #pragma unroll
  for (int j = 0; j < 8; ++j) {
    int blk = tid * 8 + j;
    if (blk < NB) {
      const int* p = partial + blk * 4;
      s.x += p[0]; s.y += p[1]; s.z += p[2]; s.w += p[3];
    }
  }
  tsum[tid] = s;
  __syncthreads();
  if (tid == 0) {
    int4 run = make_int4(0, 0, 0, 0);
    for (int i = 0; i < 256; ++i) {
      int4 v = tsum[i]; tsum[i] = run;
      run.x += v.x; run.y += v.y; run.z += v.z; run.w += v.w;
    }
    ctr[0] = run.x; ctr[1] = run.y; ctr[2] = run.z; ctr[3] = run.w;
    int off = 0;
    ctr[4] = 0;            off += run.x;
    ctr[5] = off;          off += run.y;
    ctr[6] = off;          off += run.z;
    ctr[7] = off;
  }
  __syncthreads();
  int4 run = tsum[tid];
  #pragma unroll
  for (int j = 0; j < 8; ++j) {
    int blk = tid * 8 + j;
    if (blk < NB) {
      const int* p = partial + blk * 4;
      int* bb = blockbase + blk * 4;
      bb[0] = run.x; bb[1] = run.y; bb[2] = run.z; bb[3] = run.w;
      run.x += p[0]; run.y += p[1]; run.z += p[2]; run.w += p[3];
    }
  }
  for (int i = tid; i < NT * OD; i += 256) biasc[i] = b[i] + temb[i];
}

// W [NT][IND][OD] f32 -> Wbf [NT][OD][KP] bf16 (N-major, K zero-padded beyond 228)
__global__ void wconv_kernel(const float* __restrict__ W, unsigned short* __restrict__ Wbf) {
  int row = blockIdx.x * 4 + (threadIdx.x >> 6);   // row = t*OD + n, 0..511
  int t = row >> 7, n = row & 127;
  int k0 = (threadIdx.x & 63) << 2;
  ushort4 o;
  float v0 = (k0 + 0 < IND) ? W[((size_t)t * IND + k0 + 0) * OD + n] : 0.f;
  float v1 = (k0 + 1 < IND) ? W[((size_t)t * IND + k0 + 1) * OD + n] : 0.f;
  float v2 = (k0 + 2 < IND) ? W[((size_t)t * IND + k0 + 2) * OD + n] : 0.f;
  float v3 = (k0 + 3 < IND) ? W[((size_t)t * IND + k0 + 3) * OD + n] : 0.f;
  o.x = f2bf(v0); o.y = f2bf(v1); o.z = f2bf(v2); o.w = f2bf(v3);
  *(ushort4*)(Wbf + ((size_t)row << 8) + k0) = o;
}

// deterministic SORTED fill: pos = type_off + blockbase[b][t] + in-block rank.
__global__ void fill_kernel(const int* __restrict__ types, const int* __restrict__ blockbase,
                            const int* __restrict__ ctr, int* __restrict__ bucket, int n) {
  __shared__ int wcnt[4][NT];
  __shared__ int wbase[4][NT];
  const int tid = threadIdx.x, w = tid >> 6, l = tid & 63;
  const int i = blockIdx.x * 256 + tid;
  const int t = (i < n) ? types[i] : -1;
  unsigned long long m[NT];
  #pragma unroll
  for (int q = 0; q < NT; ++q) {
    m[q] = __ballot(t == q);
    if (l == 0) wcnt[w][q] = (int)__popcll(m[q]);
  }
  __syncthreads();
  if (tid < NT) {
    int q = tid, s = 0;
    #pragma unroll
    for (int w2 = 0; w2 < 4; ++w2) { wbase[w2][q] = s; s += wcnt[w2][q]; }
  }
  __syncthreads();
  if (t >= 0) {
    int rank = wbase[w][t] + (int)__popcll(m[t] & ((1ull << l) - 1ull));
    bucket[ctr[4 + t] + blockbase[blockIdx.x * 4 + t] + rank] = i;
  }
}

// Main kernel (champion, r18): bucketed gather, swapped MFMA, direct stores.
// Swapped MFMA puts lane (bl,bh)'s acc at out[edge rt*16+bl][wid*32+bh*4(+16)]
// -> store DIRECTLY per row-subtile (acc = 8 live regs). 2 barriers/tile,
// zero epilogue LDS ops, VGPR 112 -> 4 waves/SIMD co-residency. Lever ledger:
// barriers/ordering/stage-VALU null; epilogue removal -23us; depth-2 prefetch
// -21us (occupancy halves). 391 MB at 2.66 TB/s = this gather pattern's floor.
__global__ __launch_bounds__(256) void gemm_kernel(
    const float* __restrict__ feats, const float* __restrict__ ts,
    const float* __restrict__ freqs, const unsigned short* __restrict__ Wbf,
    const float* __restrict__ biasc, const int* __restrict__ bucket,
    const int* __restrict__ ctr, float* __restrict__ out) {
  __shared__ __align__(16) char smA[64 * 512];      // A bf16 [64][256], XOR-swizzled
  __shared__ __align__(16) float sfreq[128];

  const int t = blockIdx.x;
  const int cnt = ctr[t];
  const int off = ctr[4 + t];
  const int ntiles = (cnt + 63) >> 6;
  const int chunk = (ntiles + GX - 1) / GX;
  const int t0 = blockIdx.y * chunk;
  const int t1 = min(t0 + chunk, ntiles);
  if (t0 >= t1) return;

  const int tid = threadIdx.x;
  const int wid = tid >> 6, lane = tid & 63;
  const int bl = lane & 15, bh = lane >> 4;
  const int r = tid >> 2, part = tid & 3;   // 4 threads per A-row; part = 32-elem window

  // W fragments, first MFMA operand (A-layout): lane bl <-> out-col, k-window bh*8
  short8 bfrag[8][2];
  #pragma unroll
  for (int n = 0; n < 2; ++n) {
    const unsigned short* bp =
        Wbf + (((size_t)t * OD + wid * 32 + n * 16 + bl) << 8) + (bh << 3);
    #pragma unroll
    for (int k = 0; k < 8; ++k) bfrag[k][n] = *(const short8*)(bp + k * 32);
  }
  // bias for this lane's cols: col = wid*32 + n*16 + bh*4 + j
  const float4 bv0 = *(const float4*)(biasc + t * OD + wid * 32 + bh * 4);
  const float4 bv1 = *(const float4*)(biasc + t * OD + wid * 32 + 16 + bh * 4);

  if (tid < 128) sfreq[tid] = (tid < TD) ? freqs[t * TD + tid] : 0.f;

  auto stage = [&](const float4* p, float tvv) {
    #pragma unroll
    for (int j = 0; j < 4; ++j) {
      uint4 q;
      q.x = pack2bf(p[2 * j].x, p[2 * j].y);
      q.y = pack2bf(p[2 * j].z, p[2 * j].w);
      q.z = pack2bf(p[2 * j + 1].x, p[2 * j + 1].y);
      q.w = pack2bf(p[2 * j + 1].z, p[2 * j + 1].w);
      *(uint4*)(smA + a_off(r, part * 32 + 8 * j)) = q;
    }
    #pragma unroll
    for (int j = 0; j < 4; ++j) {
      float4 f0 = *(const float4*)&sfreq[part * 32 + 8 * j];
      float4 f1 = *(const float4*)&sfreq[part * 32 + 8 * j + 4];
      uint4 q;
      q.x = pack2bf(__cosf(tvv * f0.x), __cosf(tvv * f0.y));
      q.y = pack2bf(__cosf(tvv * f0.z), __cosf(tvv * f0.w));
      q.z = pack2bf(__cosf(tvv * f1.x), __cosf(tvv * f1.y));
      q.w = pack2bf(__cosf(tvv * f1.z), __cosf(tvv * f1.w));
      *(uint4*)(smA + a_off(r, FD + part * 32 + 8 * j)) = q;
    }
  };

  // ---- prologue ----
  int e_cur = -1; float tv_cur = 0.f;
  {
    const int va = min(64, cnt - t0 * 64);
    if (r < va) { e_cur = bucket[off + t0 * 64 + r]; tv_cur = ts[e_cur]; }
  }
  float4 pf[8];
  if (e_cur >= 0) {
    const float4* src = (const float4*)(feats + (size_t)e_cur * FD + part * 32);
    #pragma unroll
    for (int c = 0; c < 8; ++c) pf[c] = src[c];
  }
  int e_b = -1; float tv_b = 0.f;
  if (t0 + 1 < t1) {
    const int vb = min(64, cnt - (t0 + 1) * 64);
    if (r < vb) { e_b = bucket[off + (t0 + 1) * 64 + r]; tv_b = ts[e_b]; }
  }
  __syncthreads();                    // sfreq visible
  if (e_cur >= 0) stage(pf, tv_cur);

  for (int tt = t0; tt < t1; ++tt) {
    const bool last = (tt == t1 - 1);
    __syncthreads();   // A(tt) ready

    // prefetch feats(tt+1) -> regs (rides under MFMA; drains at next barrier)
    if (!last && e_b >= 0) {
      const float4* src = (const float4*)(feats + (size_t)e_b * FD + part * 32);
      #pragma unroll
      for (int c = 0; c < 8; ++c) pf[c] = src[c];
    }
    // issue idx(tt+2): bucket->ts chain covered by a full iteration
    int e_c = -1; float tv_c = 0.f;
    if (tt + 2 < t1) {
      const int vc = min(64, cnt - (tt + 2) * 64);
      if (r < vc) { e_c = bucket[off + (tt + 2) * 64 + r]; tv_c = ts[e_c]; }
    }
    // edge indices of the 4 row-subtiles this lane stores (sorted bucket, L1-hot)
    const int base = tt * 64;
    const int vcnt = cnt - base;   // >0
    int se[4];
    #pragma unroll
    for (int rt = 0; rt < 4; ++rt) {
      int rr = rt * 16 + bl;
      se[rt] = (rr < vcnt) ? bucket[off + base + rr] : -1;
    }

    // ---- MFMA per row-subtile, bias in acc-init, DIRECT store ----
    __builtin_amdgcn_s_setprio(1);
    #pragma unroll
    for (int rt = 0; rt < 4; ++rt) {
      f32x4 a0, a1;
      a0[0] = bv0.x; a0[1] = bv0.y; a0[2] = bv0.z; a0[3] = bv0.w;
      a1[0] = bv1.x; a1[1] = bv1.y; a1[2] = bv1.z; a1[3] = bv1.w;
      #pragma unroll
      for (int k = 0; k < 8; ++k) {
        short8 av = *(const short8*)(smA + a_off(rt * 16 + bl, k * 32 + bh * 8));
        a0 = __builtin_amdgcn_mfma_f32_16x16x32_bf16(bfrag[k][0], av, a0, 0, 0, 0);
        a1 = __builtin_amdgcn_mfma_f32_16x16x32_bf16(bfrag[k][1], av, a1, 0, 0, 0);
      }
      if (se[rt] >= 0) {
        float* dst = out + (size_t)se[rt] * OD + wid * 32 + bh * 4;
        *(f32x4*)(dst)      = a0;
        *(f32x4*)(dst + 16) = a1;
      }
    }
    __builtin_amdgcn_s_setprio(0);
    __syncthreads();   // A reads done; prefetch+stores drained; region reusable

    if (!last) {
      if (e_b >= 0) stage(pf, tv_b);
      e_cur = e_b; tv_cur = tv_b;
      e_b = e_c; tv_b = tv_c;
    }
  }
}

// correctness fallback if ws is too small (fp32 vector path)
__global__ void naive_kernel(const float* __restrict__ feats, const float* __restrict__ ts,
                             const int* __restrict__ types, const float* __restrict__ W,
                             const float* __restrict__ b, const float* __restrict__ temb,
                             const float* __restrict__ freqs, float* __restrict__ out) {
  __shared__ float comb[IND];
  int e = blockIdx.x;
  int t = types[e];
  int tid = threadIdx.x;  // 128 threads
  comb[tid] = feats[(size_t)e * FD + tid];
  if (tid < TD) comb[FD + tid] = __cosf(ts[e] * freqs[t * TD + tid]);
  __syncthreads();
  float acc = b[t * OD + tid] + temb[t * OD + tid];
  for (int k = 0; k < IND; ++k) acc += comb[k] * W[((size_t)t * IND + k) * OD + tid];
  out[(size_t)e * OD + tid] = acc;
}

extern "C" void kernel_launch(void* const* d_in, const int* in_sizes, int n_in,
                              void* d_out, int out_size, void* d_ws, size_t ws_size,
                              hipStream_t stream) {
  const float* feats = (const float*)d_in[0];
  const float* ts    = (const float*)d_in[1];
  const int*   types = (const int*)d_in[2];
  const float* W     = (const float*)d_in[3];
  const float* bb    = (const float*)d_in[4];
  const float* temb  = (const float*)d_in[5];
  const float* freqs = (const float*)d_in[6];
  float* out = (float*)d_out;

  if (ws_size < WS_NEED) {
    naive_kernel<<<E_N, 128, 0, stream>>>(feats, ts, types, W, bb, temb, freqs, out);
    return;
  }

  char* ws = (char*)d_ws;
  int* bucket = (int*)(ws + BUCKET_OFF);
  unsigned short* Wbf = (unsigned short*)(ws + WBF_OFF);
  float* biasc = (float*)(ws + BIASC_OFF);
  int* ctr = (int*)(ws + CTR_OFF);
  int* partial = (int*)(ws + PART_OFF);
  int* blockbase = (int*)(ws + BBASE_OFF);

  hist_kernel<<<NB, 256, 0, stream>>>(types, partial, E_N);
  scan_kernel<<<1, 256, 0, stream>>>(partial, blockbase, ctr, bb, temb, biasc);
  wconv_kernel<<<(NT * OD) / 4, 256, 0, stream>>>(W, Wbf);
  fill_kernel<<<NB, 256, 0, stream>>>(types, blockbase, ctr, bucket, E_N);
  dim3 g(NT, GX);
  gemm_kernel<<<g, 256, 0, stream>>>(feats, ts, freqs, Wbf, biasc, bucket, ctr, out);
}